// Round 9
// baseline (225.932 us; speedup 1.0000x reference)
//
#include <hip/hip_runtime.h>
#include <stdint.h>
#include <stddef.h>

// Problem constants (B, F, D) = (1024, 16, 64); P = 120
constexpr int NB = 1024;
constexpr int NF = 16;
constexpr int ND = 64;
constexpr int NP = 120;
constexpr int KD = ND * ND;          // 4096 contraction length per pair
constexpr int OUT_STRIDE = NP * ND;  // 7680 floats per batch row

constexpr int BM = 256;              // batch rows per block
constexpr int NS = 32;               // stages; each stage covers 2 a-columns (BK = 128)
// 8 waves tile the 256x64 output as 4 m-groups (64 rows) x 2 n-groups (32 cols),
// each wave = 2 x (32x32) MFMA tiles using v_mfma_f32_32x32x16_f16 (2495 TF pipe
// vs 2075 for 16x16 — m119/m06), half the MFMA instruction count.

using floatx4  = __attribute__((ext_vector_type(4))) float;
using floatx16 = __attribute__((ext_vector_type(16))) float;
using half8    = __attribute__((ext_vector_type(8))) _Float16;
using half2v   = __attribute__((ext_vector_type(2))) _Float16;
using fp16x2   = __attribute__((ext_vector_type(2))) __fp16;   // cvt_pkrtz return type
using uint4v   = __attribute__((ext_vector_type(4))) uint32_t;

constexpr int WCOL = ND * ND / 64 * 64;    // u16 per W column tile (64 n x 64 c) = 4096
constexpr int WSTG = 2 * WCOL;             // u16 per stage (2 cols) = 8192 (16 KiB)

// pack 2 f32 -> 2 fp16 (v_cvt_pkrtz_f16_f32, 1 VALU op)
__device__ __forceinline__ half2v pkh2(float f0, float f1) {
    fp16x2 h = __builtin_amdgcn_cvt_pkrtz(f0, f1);
    return __builtin_bit_cast(half2v, h);
}
__device__ __forceinline__ uint32_t pk16(float f0, float f1) {
    fp16x2 h = __builtin_amdgcn_cvt_pkrtz(f0, f1);
    return __builtin_bit_cast(uint32_t, h);
}
__device__ __forceinline__ uint16_t f16bits(float f) {
    return __builtin_bit_cast(uint16_t, (_Float16)f);   // RNE scalar cvt
}

// Barrier that does NOT drain vmcnt: LDS ordering only (global W prefetch
// stays in flight across barriers; __syncthreads would force vmcnt(0)).
__device__ __forceinline__ void lds_barrier() {
    asm volatile("s_waitcnt lgkmcnt(0)" ::: "memory");
    __builtin_amdgcn_s_barrier();
    asm volatile("" ::: "memory");
}

__global__ __launch_bounds__(512, 4)
void outer_kernel(const float* __restrict__ x, const float* __restrict__ W,
                  const float* __restrict__ bias, float* __restrict__ out)
{
    // xi^T fp16, layout [a][wm][r32][mt] -> one ds_read_b32 per (a) per wave
    __shared__ uint16_t lds_xit[ND * BM];        // 32,768 B
    __shared__ uint16_t lds_bt[2 * WSTG];        // W stage dbuf: 32,768 B (total 65,536 -> 2 blocks/CU)

    const int p  = blockIdx.x;        // pair 0..119
    const int b0 = blockIdx.y * BM;   // batch tile origin

    // triu_indices(16, k=1) order
    int icol = 0, rem = p;
    while (rem >= NF - 1 - icol) { rem -= NF - 1 - icol; ++icol; }
    const int jcol = icol + 1 + rem;

    const int t    = threadIdx.x;
    const int wave = t >> 6;
    const int lane = t & 63;
    const int r32  = lane & 31;
    const int kh   = lane >> 5;       // k-half (0/1) for 32x32x16 fragments
    const int wm   = wave & 3;        // m-group: rows wm*64 .. wm*64+63
    const int wn   = wave >> 2;       // n-group: cols wn*32 .. wn*32+31

    // ---- stage xi transposed: lds_xit[a*256 + (m>>6)*64 + (m&31)*2 + ((m>>5)&1)] ----
    {
        const int mrow  = t >> 1;
        const int chalf = (t & 1) * 32;
        const int dbase = (mrow >> 6) * 64 + (mrow & 31) * 2 + ((mrow >> 5) & 1);
        const float* src = x + (size_t)(b0 + mrow) * (NF * ND) + icol * ND + chalf;
        #pragma unroll
        for (int c = 0; c < 32; c += 4) {
            floatx4 v = *(const floatx4*)(src + c);
            lds_xit[(chalf + c + 0) * BM + dbase] = f16bits(v.x);
            lds_xit[(chalf + c + 1) * BM + dbase] = f16bits(v.y);
            lds_xit[(chalf + c + 2) * BM + dbase] = f16bits(v.z);
            lds_xit[(chalf + c + 3) * BM + dbase] = f16bits(v.w);
        }
    }

    // ---- loop-invariant xj as fp16 pairs, matching the 32x32x16 A-fragment ----
    // lane owns A[m = mt*32 + r32][k = kh*8 + j]; chunk kc covers c = kc*16 + kh*8 + j
    half2v xjh[2][16];
    #pragma unroll
    for (int mt = 0; mt < 2; ++mt) {
        const float* srow = x + (size_t)(b0 + wm*64 + mt*32 + r32) * (NF * ND)
                              + jcol * ND + kh * 8;
        #pragma unroll
        for (int kc = 0; kc < 4; ++kc) {
            floatx4 v0 = *(const floatx4*)(srow + kc * 16);
            floatx4 v1 = *(const floatx4*)(srow + kc * 16 + 4);
            xjh[mt][kc*4 + 0] = pkh2(v0.x, v0.y);
            xjh[mt][kc*4 + 1] = pkh2(v0.z, v0.w);
            xjh[mt][kc*4 + 2] = pkh2(v1.x, v1.y);
            xjh[mt][kc*4 + 3] = pkh2(v1.z, v1.w);
        }
    }

    // ---- W staging: thread covers (n_st, granule cg); XOR-swizzled slot cg ^ (n_st & 7) ----
    const int n_st = t >> 3;
    const int cg   = t & 7;
    const float* wsrc = W + ((size_t)p * ND + n_st) * KD + cg * 8;
    uint16_t* bdst0 = &lds_bt[n_st * ND + ((cg ^ (n_st & 7)) * 8)];

    auto loadW2 = [&](int s2, floatx4* w) {        // issue global loads of stage s2 (cols 2s2, 2s2+1)
        const float* wp = wsrc + (size_t)(2 * s2) * ND;
        w[0] = *(const floatx4*)(wp);
        w[1] = *(const floatx4*)(wp + 4);
        w[2] = *(const floatx4*)(wp + ND);
        w[3] = *(const floatx4*)(wp + ND + 4);
    };
    auto packW2 = [&](int d, const floatx4* w) {   // pack stage regs -> buf d (2 cols)
        #pragma unroll
        for (int sub = 0; sub < 2; ++sub) {
            uint16_t* bd = bdst0 + d * WSTG + sub * WCOL;
            uint4v q0 = (uint4v){ pk16(w[sub*2].x,   w[sub*2].y),   pk16(w[sub*2].z,   w[sub*2].w),
                                  pk16(w[sub*2+1].x, w[sub*2+1].y), pk16(w[sub*2+1].z, w[sub*2+1].w) };
            *(uint4v*)(bd) = q0;
        }
    };

    floatx16 acc[2] = {};    // fp32 C-accumulators, one 32x32 tile per mt

    // B-fragment base: row n = wn*32 + r32; granule for (kc, kh) is 2kc + kh, swizzled by n&7
    const int nrow   = wn*32 + r32;
    const int bbase  = nrow * ND;
    const int bswz   = (r32 & 7);

    auto compute = [&](int s, int cur) {
        const int a0 = 2 * s;
        const uint16_t* rb = lds_bt + cur * WSTG;

        // xi: one b32 per a gives both mt values (lanes l and l+32 broadcast)
        const uint32_t xi0 = *(const uint32_t*)&lds_xit[a0 * BM + wm*64 + r32*2];
        const uint32_t xi1 = *(const uint32_t*)&lds_xit[(a0 + 1) * BM + wm*64 + r32*2];
        const half2v xs00 = __builtin_bit_cast(half2v, __builtin_amdgcn_perm(xi0, xi0, 0x01000100u)); // a0, mt0
        const half2v xs01 = __builtin_bit_cast(half2v, __builtin_amdgcn_perm(xi0, xi0, 0x03020302u)); // a0, mt1
        const half2v xs10 = __builtin_bit_cast(half2v, __builtin_amdgcn_perm(xi1, xi1, 0x01000100u)); // a1, mt0
        const half2v xs11 = __builtin_bit_cast(half2v, __builtin_amdgcn_perm(xi1, xi1, 0x03020302u)); // a1, mt1

        __builtin_amdgcn_s_setprio(1);
        #pragma unroll
        for (int kc = 0; kc < 4; ++kc) {
            const int boff = bbase + (((2*kc + kh) ^ bswz) * 8);
            half8 bf0 = *(const half8*)&rb[boff];          // col a0
            half8 bf1 = *(const half8*)&rb[WCOL + boff];   // col a1

            union { half8 h8; half2v h2[4]; } a00, a01, a10, a11;
            #pragma unroll
            for (int q = 0; q < 4; ++q) {
                const half2v xv = xjh[0][kc*4 + q];
                const half2v yv = xjh[1][kc*4 + q];
                a00.h2[q] = xs00 * xv;   // v_pk_mul_f16
                a10.h2[q] = xs10 * xv;
                a01.h2[q] = xs01 * yv;
                a11.h2[q] = xs11 * yv;
            }
            acc[0] = __builtin_amdgcn_mfma_f32_32x32x16_f16(a00.h8, bf0, acc[0], 0, 0, 0);
            acc[1] = __builtin_amdgcn_mfma_f32_32x32x16_f16(a01.h8, bf0, acc[1], 0, 0, 0);
            acc[0] = __builtin_amdgcn_mfma_f32_32x32x16_f16(a10.h8, bf1, acc[0], 0, 0, 0);
            acc[1] = __builtin_amdgcn_mfma_f32_32x32x16_f16(a11.h8, bf1, acc[1], 0, 0, 0);
        }
        __builtin_amdgcn_s_setprio(0);
    };

    // ---- prologue: stage 0 -> buf0; stage 1 loads in regs; publish ----
    floatx4 wpk[4], wtmp[4];
    loadW2(0, wtmp);
    packW2(0, wtmp);
    loadW2(1, wpk);
    __syncthreads();   // one-time full barrier (xit + buf0 visible)

    // ---- main loop: 32 stages, one lgkm-only barrier each ----
    #pragma unroll 1
    for (int s = 0; s < NS; ++s) {
        const int cur = s & 1;
        if (s + 1 < NS) packW2(cur ^ 1, wpk);   // write-early (wpk loaded one stage ago)
        if (s + 2 < NS) loadW2(s + 2, wpk);     // prefetch crosses barriers, never drained
        compute(s, cur);
        lds_barrier();
    }

    // ---- epilogue: bias + store. 32x32 C/D: col = lane&31, row = (reg&3)+8*(reg>>2)+4*kh ----
    const float bb = bias[p * ND + wn*32 + r32];
    #pragma unroll
    for (int mt = 0; mt < 2; ++mt) {
        #pragma unroll
        for (int reg = 0; reg < 16; ++reg) {
            const int row = b0 + wm*64 + mt*32 + (reg & 3) + 8*(reg >> 2) + 4*kh;
            out[(size_t)row * OUT_STRIDE + p * ND + wn*32 + r32] = acc[mt][reg] + bb;
        }
    }
}

extern "C" void kernel_launch(void* const* d_in, const int* in_sizes, int n_in,
                              void* d_out, int out_size, void* d_ws, size_t ws_size,
                              hipStream_t stream) {
    const float* x    = (const float*)d_in[0];  // (1024, 16, 64)
    const float* W    = (const float*)d_in[1];  // (120, 64, 4096)
    const float* bias = (const float*)d_in[2];  // (120, 64)
    float* out = (float*)d_out;                 // (1024, 120, 64)

    dim3 grid(NP, NB / BM);    // 480 blocks; same-p blocks land on one XCD (120 % 8 == 0)
    outer_kernel<<<grid, 512, 0, stream>>>(x, W, bias, out);
}